// Round 11
// baseline (79.006 us; speedup 1.0000x reference)
//
#include <hip/hip_runtime.h>

#define B 8
#define H 256
#define W 512
#define C 16
#define FIL 16
#define NP 8
#define PH 32      // H/NP
#define W2 256     // W/2
#define CH 8       // width chunks for pool kernel
#define POOL_ELEMS (B*NP*W2*C)   // 327680 floats

typedef float f32x4 __attribute__((ext_vector_type(4)));

// ---------------- Kernel 1: average pool (32x2), H-split partials ---------
__global__ __launch_bounds__(256) void pool_kernel(const float* __restrict__ fm,
                                                   float* __restrict__ PP) {
    int blk = blockIdx.x;
    int rh = blk & 1;
    int ch = (blk >> 1) & (CH - 1);
    int bi = blk >> 4;               // b*NP + i
    int t = threadIdx.x;
    const float4* src = (const float4*)fm + (size_t)bi * (PH * W * C / 4)
                        + rh * 16 * (W * C / 4) + ch * 256 + t;
    float4 acc = make_float4(0.f, 0.f, 0.f, 0.f);
#pragma unroll 16
    for (int hh = 0; hh < 16; ++hh) {
        float4 v = src[hh * (W * C / 4)];
        acc.x += v.x; acc.y += v.y; acc.z += v.z; acc.w += v.w;
    }
    __shared__ float4 s[256];
    s[t] = acc;
    __syncthreads();
    if (t < 128) {
        int u = t >> 2, q = t & 3;        // pooled-pixel-local, channel quad
        float4 a = s[u * 8 + q], b2 = s[u * 8 + 4 + q];
        float4 r = make_float4((a.x + b2.x) * (1.0f / 64.0f),
                               (a.y + b2.y) * (1.0f / 64.0f),
                               (a.z + b2.z) * (1.0f / 64.0f),
                               (a.w + b2.w) * (1.0f / 64.0f));
        float4* out = (float4*)(PP + (size_t)rh * POOL_ELEMS + (size_t)bi * (W2 * C))
                      + ch * 128 + t;
        *out = r;
    }
}

// ---------------- Kernel 2: masked 5x5 conv (rows 0,4 only), row + col ----
__global__ __launch_bounds__(256) void conv_kernel(const float* __restrict__ PP,
                                                   const float* __restrict__ kern,
                                                   const float* __restrict__ bias,
                                                   float* __restrict__ ROW,
                                                   float* __restrict__ COL) {
    int blk = blockIdx.x;
    int jq = blk & 3;
    int rc = (blk >> 2) & 1;
    int bi = blk >> 3;               // 0..63
    int b = bi >> 3, i = bi & 7;
    int t = threadIdx.x;
    __shared__ float K0[5 * C * FIL];
    __shared__ float K4[5 * C * FIL];
    for (int idx = t; idx < 5 * C * FIL; idx += 256) {
        K0[idx] = kern[idx];
        K4[idx] = kern[4 * 5 * C * FIL + idx];
    }
    __syncthreads();
    int px = t >> 2;
    int j = jq * 64 + px;
    int fq = (t & 3) * 4;
    const float* Pb0 = PP + (size_t)b * (NP * W2 * C);
    const float* Pb1 = Pb0 + POOL_ELEMS;
    float acc0 = bias[fq], acc1 = bias[fq + 1], acc2 = bias[fq + 2], acc3 = bias[fq + 3];

    if (rc == 0) {
#pragma unroll
        for (int rr = 0; rr < 2; ++rr) {
            int ii = i + (rr ? 2 : -2);
            if (ii < 0 || ii >= NP) continue;
            const float* Kr = (rr ? K4 : K0) + fq;
            for (int s = 0; s < 5; ++s) {
                int jj = j + s - 2;
                if (jj < 0 || jj >= W2) continue;
                const float4* p40 = (const float4*)(Pb0 + (size_t)(ii * W2 + jj) * C);
                const float4* p41 = (const float4*)(Pb1 + (size_t)(ii * W2 + jj) * C);
#pragma unroll
                for (int cq = 0; cq < 4; ++cq) {
                    float4 pa = p40[cq], pb = p41[cq];
                    float4 pv = make_float4(pa.x + pb.x, pa.y + pb.y,
                                            pa.z + pb.z, pa.w + pb.w);
                    const float* kk = Kr + (s * C + cq * 4) * FIL;
                    acc0 = fmaf(pv.x, kk[0], acc0); acc1 = fmaf(pv.x, kk[1], acc1);
                    acc2 = fmaf(pv.x, kk[2], acc2); acc3 = fmaf(pv.x, kk[3], acc3);
                    acc0 = fmaf(pv.y, kk[FIL + 0], acc0); acc1 = fmaf(pv.y, kk[FIL + 1], acc1);
                    acc2 = fmaf(pv.y, kk[FIL + 2], acc2); acc3 = fmaf(pv.y, kk[FIL + 3], acc3);
                    acc0 = fmaf(pv.z, kk[2 * FIL + 0], acc0); acc1 = fmaf(pv.z, kk[2 * FIL + 1], acc1);
                    acc2 = fmaf(pv.z, kk[2 * FIL + 2], acc2); acc3 = fmaf(pv.z, kk[2 * FIL + 3], acc3);
                    acc0 = fmaf(pv.w, kk[3 * FIL + 0], acc0); acc1 = fmaf(pv.w, kk[3 * FIL + 1], acc1);
                    acc2 = fmaf(pv.w, kk[3 * FIL + 2], acc2); acc3 = fmaf(pv.w, kk[3 * FIL + 3], acc3);
                }
            }
        }
        float4* o = (float4*)(ROW + ((size_t)(b * NP + i) * W2 + j) * FIL + fq);
        *o = make_float4(fmaxf(acc0, 0.f), fmaxf(acc1, 0.f), fmaxf(acc2, 0.f), fmaxf(acc3, 0.f));
    } else {
        for (int s = 0; s < 5; ++s) {
            int ii = i + s - 2;
            if (ii < 0 || ii >= NP) continue;
#pragma unroll
            for (int rr = 0; rr < 2; ++rr) {
                int jj = j + (rr ? 2 : -2);
                if (jj < 0 || jj >= W2) continue;
                const float* Kr = (rr ? K4 : K0) + fq;
                const float4* p40 = (const float4*)(Pb0 + (size_t)(ii * W2 + jj) * C);
                const float4* p41 = (const float4*)(Pb1 + (size_t)(ii * W2 + jj) * C);
#pragma unroll
                for (int cq = 0; cq < 4; ++cq) {
                    float4 pa = p40[cq], pb = p41[cq];
                    float4 pv = make_float4(pa.x + pb.x, pa.y + pb.y,
                                            pa.z + pb.z, pa.w + pb.w);
                    const float* kk = Kr + (s * C + cq * 4) * FIL;
                    acc0 = fmaf(pv.x, kk[0], acc0); acc1 = fmaf(pv.x, kk[1], acc1);
                    acc2 = fmaf(pv.x, kk[2], acc2); acc3 = fmaf(pv.x, kk[3], acc3);
                    acc0 = fmaf(pv.y, kk[FIL + 0], acc0); acc1 = fmaf(pv.y, kk[FIL + 1], acc1);
                    acc2 = fmaf(pv.y, kk[FIL + 2], acc2); acc3 = fmaf(pv.y, kk[FIL + 3], acc3);
                    acc0 = fmaf(pv.z, kk[2 * FIL + 0], acc0); acc1 = fmaf(pv.z, kk[2 * FIL + 1], acc1);
                    acc2 = fmaf(pv.z, kk[2 * FIL + 2], acc2); acc3 = fmaf(pv.z, kk[2 * FIL + 3], acc3);
                    acc0 = fmaf(pv.w, kk[3 * FIL + 0], acc0); acc1 = fmaf(pv.w, kk[3 * FIL + 1], acc1);
                    acc2 = fmaf(pv.w, kk[3 * FIL + 2], acc2); acc3 = fmaf(pv.w, kk[3 * FIL + 3], acc3);
                }
            }
        }
        float4* o = (float4*)(COL + ((size_t)(b * NP + i) * W2 + j) * FIL + fq);
        *o = make_float4(fmaxf(acc0, 0.f), fmaxf(acc1, 0.f), fmaxf(acc2, 0.f), fmaxf(acc3, 0.f));
    }
}

// ---------------- Kernel 3: bilinear upsample + diff + concat -------------
// grid = B*H (XCD-swizzled), 256 threads. Thread=(pixel,quad): one fm load
// -> three outputs. NT stores: no-allocate write stream keeps fm resident in
// the 256 MB L3 (pool warmed it) so up's fm reads stay L3 hits end-to-end.
__global__ __launch_bounds__(256) void up_kernel(const float* __restrict__ fm,
                                                 const float* __restrict__ ROW,
                                                 const float* __restrict__ COL,
                                                 float* __restrict__ out) {
    int bid = blockIdx.x;
    int blk = (bid & 7) * 256 + (bid >> 3);   // bijective: XCD k -> b = k
    int b = blk >> 8, h = blk & 255;
    int t = threadIdx.x;
    __shared__ float Rs[W2 * C];   // H-lerped row_op row
    __shared__ float Cs[W2 * C];   // H-lerped col_op row

    float sh = (h + 0.5f) * (1.0f / 32.0f) - 0.5f;
    float flh = floorf(sh);
    float fh = sh - flh;
    int i0 = (int)flh;
    int i1 = min(i0 + 1, NP - 1);
    i0 = max(i0, 0);
    float wa = 1.0f - fh, wb = fh;

    const float4* r0 = (const float4*)(ROW + (size_t)(b * NP + i0) * (W2 * C));
    const float4* r1 = (const float4*)(ROW + (size_t)(b * NP + i1) * (W2 * C));
    const float4* c0 = (const float4*)(COL + (size_t)(b * NP + i0) * (W2 * C));
    const float4* c1 = (const float4*)(COL + (size_t)(b * NP + i1) * (W2 * C));
#pragma unroll
    for (int k = 0; k < 4; ++k) {
        int idx = t + k * 256;
        float4 a = r0[idx], bv = r1[idx];
        ((float4*)Rs)[idx] = make_float4(wa * a.x + wb * bv.x, wa * a.y + wb * bv.y,
                                         wa * a.z + wb * bv.z, wa * a.w + wb * bv.w);
        float4 ca = c0[idx], cb = c1[idx];
        ((float4*)Cs)[idx] = make_float4(wa * ca.x + wb * cb.x, wa * ca.y + wb * cb.y,
                                         wa * ca.z + wb * cb.z, wa * ca.w + wb * cb.w);
    }
    __syncthreads();

    int cq = t & 3;                // channel quad 0..3
    int p0 = t >> 2;               // 0..63
    int cc = cq * 4;

    const float4* fmr = (const float4*)(fm + (size_t)(b * H + h) * (W * C));
    f32x4* orow = (f32x4*)(out + (size_t)(b * H + h) * (W * 48));
#pragma unroll
    for (int k = 0; k < 8; ++k) {
        int p = k * 64 + p0;
        float4 v = fmr[p * 4 + cq];

        float sw = 0.5f * p - 0.25f;
        float flw = floorf(sw);
        float fw = sw - flw;
        int j0i = max((int)flw, 0);
        int j1i = min((int)flw + 1, W2 - 1);
        float iw = 1.0f - fw;

        const float4 Ra = *(const float4*)(Rs + j0i * 16 + cc);
        const float4 Rb = *(const float4*)(Rs + j1i * 16 + cc);
        const float4 Ca = *(const float4*)(Cs + j0i * 16 + cc);
        const float4 Cb = *(const float4*)(Cs + j1i * 16 + cc);

        f32x4 vv = { v.x, v.y, v.z, v.w };
        f32x4 dr = { v.x - (iw * Ra.x + fw * Rb.x),
                     v.y - (iw * Ra.y + fw * Rb.y),
                     v.z - (iw * Ra.z + fw * Rb.z),
                     v.w - (iw * Ra.w + fw * Rb.w) };
        f32x4 dc = { v.x - (iw * Ca.x + fw * Cb.x),
                     v.y - (iw * Ca.y + fw * Cb.y),
                     v.z - (iw * Ca.z + fw * Cb.z),
                     v.w - (iw * Ca.w + fw * Cb.w) };

        __builtin_nontemporal_store(vv, &orow[p * 12 + cq]);      // copy
        __builtin_nontemporal_store(dr, &orow[p * 12 + 4 + cq]);  // fm-row_up
        __builtin_nontemporal_store(dc, &orow[p * 12 + 8 + cq]);  // fm-col_up
    }
}

extern "C" void kernel_launch(void* const* d_in, const int* in_sizes, int n_in,
                              void* d_out, int out_size, void* d_ws, size_t ws_size,
                              hipStream_t stream) {
    const float* fm   = (const float*)d_in[0];
    const float* kern = (const float*)d_in[1];
    const float* bias = (const float*)d_in[2];
    float* out = (float*)d_out;
    float* PP  = (float*)d_ws;                 // 2 x POOL_ELEMS partials
    float* ROW = PP + 2 * POOL_ELEMS;
    float* COL = ROW + POOL_ELEMS;

    pool_kernel<<<B * NP * CH * 2, 256, 0, stream>>>(fm, PP);
    conv_kernel<<<512, 256, 0, stream>>>(PP, kern, bias, ROW, COL);
    up_kernel<<<B * H, 256, 0, stream>>>(fm, ROW, COL, out);
}

// Round 12
// 63.752 us; speedup vs baseline: 1.2393x; 1.2393x over previous
//
#include <hip/hip_runtime.h>

#define B 8
#define H 256
#define W 512
#define C 16
#define FIL 16
#define NP 8
#define PH 32      // H/NP
#define W2 256     // W/2
#define CH 8       // width chunks for pool kernel
#define POOL_ELEMS (B*NP*W2*C)   // 327680 floats

typedef float f32x4 __attribute__((ext_vector_type(4)));

// ---------------- Kernel 1: average pool (32x2), H-split partials ---------
__global__ __launch_bounds__(256) void pool_kernel(const float* __restrict__ fm,
                                                   float* __restrict__ PP) {
    int blk = blockIdx.x;
    int rh = blk & 1;
    int ch = (blk >> 1) & (CH - 1);
    int bi = blk >> 4;               // b*NP + i
    int t = threadIdx.x;
    const float4* src = (const float4*)fm + (size_t)bi * (PH * W * C / 4)
                        + rh * 16 * (W * C / 4) + ch * 256 + t;
    float4 acc = make_float4(0.f, 0.f, 0.f, 0.f);
#pragma unroll 16
    for (int hh = 0; hh < 16; ++hh) {
        float4 v = src[hh * (W * C / 4)];
        acc.x += v.x; acc.y += v.y; acc.z += v.z; acc.w += v.w;
    }
    __shared__ float4 s[256];
    s[t] = acc;
    __syncthreads();
    if (t < 128) {
        int u = t >> 2, q = t & 3;        // pooled-pixel-local, channel quad
        float4 a = s[u * 8 + q], b2 = s[u * 8 + 4 + q];
        float4 r = make_float4((a.x + b2.x) * (1.0f / 64.0f),
                               (a.y + b2.y) * (1.0f / 64.0f),
                               (a.z + b2.z) * (1.0f / 64.0f),
                               (a.w + b2.w) * (1.0f / 64.0f));
        float4* out = (float4*)(PP + (size_t)rh * POOL_ELEMS + (size_t)bi * (W2 * C))
                      + ch * 128 + t;
        *out = r;
    }
}

// ---------------- Kernel 2: masked 5x5 conv (rows 0,4 only), row + col ----
__global__ __launch_bounds__(256) void conv_kernel(const float* __restrict__ PP,
                                                   const float* __restrict__ kern,
                                                   const float* __restrict__ bias,
                                                   float* __restrict__ ROW,
                                                   float* __restrict__ COL) {
    int blk = blockIdx.x;
    int jq = blk & 3;
    int rc = (blk >> 2) & 1;
    int bi = blk >> 3;               // 0..63
    int b = bi >> 3, i = bi & 7;
    int t = threadIdx.x;
    __shared__ float K0[5 * C * FIL];
    __shared__ float K4[5 * C * FIL];
    for (int idx = t; idx < 5 * C * FIL; idx += 256) {
        K0[idx] = kern[idx];
        K4[idx] = kern[4 * 5 * C * FIL + idx];
    }
    __syncthreads();
    int px = t >> 2;
    int j = jq * 64 + px;
    int fq = (t & 3) * 4;
    const float* Pb0 = PP + (size_t)b * (NP * W2 * C);
    const float* Pb1 = Pb0 + POOL_ELEMS;
    float acc0 = bias[fq], acc1 = bias[fq + 1], acc2 = bias[fq + 2], acc3 = bias[fq + 3];

    if (rc == 0) {
#pragma unroll
        for (int rr = 0; rr < 2; ++rr) {
            int ii = i + (rr ? 2 : -2);
            if (ii < 0 || ii >= NP) continue;
            const float* Kr = (rr ? K4 : K0) + fq;
            for (int s = 0; s < 5; ++s) {
                int jj = j + s - 2;
                if (jj < 0 || jj >= W2) continue;
                const float4* p40 = (const float4*)(Pb0 + (size_t)(ii * W2 + jj) * C);
                const float4* p41 = (const float4*)(Pb1 + (size_t)(ii * W2 + jj) * C);
#pragma unroll
                for (int cq = 0; cq < 4; ++cq) {
                    float4 pa = p40[cq], pb = p41[cq];
                    float4 pv = make_float4(pa.x + pb.x, pa.y + pb.y,
                                            pa.z + pb.z, pa.w + pb.w);
                    const float* kk = Kr + (s * C + cq * 4) * FIL;
                    acc0 = fmaf(pv.x, kk[0], acc0); acc1 = fmaf(pv.x, kk[1], acc1);
                    acc2 = fmaf(pv.x, kk[2], acc2); acc3 = fmaf(pv.x, kk[3], acc3);
                    acc0 = fmaf(pv.y, kk[FIL + 0], acc0); acc1 = fmaf(pv.y, kk[FIL + 1], acc1);
                    acc2 = fmaf(pv.y, kk[FIL + 2], acc2); acc3 = fmaf(pv.y, kk[FIL + 3], acc3);
                    acc0 = fmaf(pv.z, kk[2 * FIL + 0], acc0); acc1 = fmaf(pv.z, kk[2 * FIL + 1], acc1);
                    acc2 = fmaf(pv.z, kk[2 * FIL + 2], acc2); acc3 = fmaf(pv.z, kk[2 * FIL + 3], acc3);
                    acc0 = fmaf(pv.w, kk[3 * FIL + 0], acc0); acc1 = fmaf(pv.w, kk[3 * FIL + 1], acc1);
                    acc2 = fmaf(pv.w, kk[3 * FIL + 2], acc2); acc3 = fmaf(pv.w, kk[3 * FIL + 3], acc3);
                }
            }
        }
        float4* o = (float4*)(ROW + ((size_t)(b * NP + i) * W2 + j) * FIL + fq);
        *o = make_float4(fmaxf(acc0, 0.f), fmaxf(acc1, 0.f), fmaxf(acc2, 0.f), fmaxf(acc3, 0.f));
    } else {
        for (int s = 0; s < 5; ++s) {
            int ii = i + s - 2;
            if (ii < 0 || ii >= NP) continue;
#pragma unroll
            for (int rr = 0; rr < 2; ++rr) {
                int jj = j + (rr ? 2 : -2);
                if (jj < 0 || jj >= W2) continue;
                const float* Kr = (rr ? K4 : K0) + fq;
                const float4* p40 = (const float4*)(Pb0 + (size_t)(ii * W2 + jj) * C);
                const float4* p41 = (const float4*)(Pb1 + (size_t)(ii * W2 + jj) * C);
#pragma unroll
                for (int cq = 0; cq < 4; ++cq) {
                    float4 pa = p40[cq], pb = p41[cq];
                    float4 pv = make_float4(pa.x + pb.x, pa.y + pb.y,
                                            pa.z + pb.z, pa.w + pb.w);
                    const float* kk = Kr + (s * C + cq * 4) * FIL;
                    acc0 = fmaf(pv.x, kk[0], acc0); acc1 = fmaf(pv.x, kk[1], acc1);
                    acc2 = fmaf(pv.x, kk[2], acc2); acc3 = fmaf(pv.x, kk[3], acc3);
                    acc0 = fmaf(pv.y, kk[FIL + 0], acc0); acc1 = fmaf(pv.y, kk[FIL + 1], acc1);
                    acc2 = fmaf(pv.y, kk[FIL + 2], acc2); acc3 = fmaf(pv.y, kk[FIL + 3], acc3);
                    acc0 = fmaf(pv.z, kk[2 * FIL + 0], acc0); acc1 = fmaf(pv.z, kk[2 * FIL + 1], acc1);
                    acc2 = fmaf(pv.z, kk[2 * FIL + 2], acc2); acc3 = fmaf(pv.z, kk[2 * FIL + 3], acc3);
                    acc0 = fmaf(pv.w, kk[3 * FIL + 0], acc0); acc1 = fmaf(pv.w, kk[3 * FIL + 1], acc1);
                    acc2 = fmaf(pv.w, kk[3 * FIL + 2], acc2); acc3 = fmaf(pv.w, kk[3 * FIL + 3], acc3);
                }
            }
        }
        float4* o = (float4*)(COL + ((size_t)(b * NP + i) * W2 + j) * FIL + fq);
        *o = make_float4(fmaxf(acc0, 0.f), fmaxf(acc1, 0.f), fmaxf(acc2, 0.f), fmaxf(acc3, 0.f));
    }
}

// ---------------- Kernel 3: bilinear upsample + diff + concat -------------
// grid = B*H (XCD-swizzled), 256 threads. Compute: thread=(pixel,quad), one
// fm load -> three outputs. Store: LDS-staged 64-pixel chunk, re-read at
// stride-1, NT-stored 1KB-contiguous per wave. Tests the last untried cell:
// NT(no-allocate, keeps pool-warmed fm in L3) x contiguous(no NT scatter
// penalty, cf. R11's +14us) x 1x-loads (no issue bottleneck mask, cf. R4).
__global__ __launch_bounds__(256) void up_kernel(const float* __restrict__ fm,
                                                 const float* __restrict__ ROW,
                                                 const float* __restrict__ COL,
                                                 float* __restrict__ out) {
    int bid = blockIdx.x;
    int blk = (bid & 7) * 256 + (bid >> 3);   // bijective: XCD k -> b = k
    int b = blk >> 8, h = blk & 255;
    int t = threadIdx.x;
    __shared__ float Rs[W2 * C];       // H-lerped row_op row (16 KB)
    __shared__ float Cs[W2 * C];       // H-lerped col_op row (16 KB)
    __shared__ float4 stage[768];      // 64-pixel output chunk (12 KB)

    float sh = (h + 0.5f) * (1.0f / 32.0f) - 0.5f;
    float flh = floorf(sh);
    float fh = sh - flh;
    int i0 = (int)flh;
    int i1 = min(i0 + 1, NP - 1);
    i0 = max(i0, 0);
    float wa = 1.0f - fh, wb = fh;

    const float4* r0 = (const float4*)(ROW + (size_t)(b * NP + i0) * (W2 * C));
    const float4* r1 = (const float4*)(ROW + (size_t)(b * NP + i1) * (W2 * C));
    const float4* c0 = (const float4*)(COL + (size_t)(b * NP + i0) * (W2 * C));
    const float4* c1 = (const float4*)(COL + (size_t)(b * NP + i1) * (W2 * C));
#pragma unroll
    for (int k = 0; k < 4; ++k) {
        int idx = t + k * 256;
        float4 a = r0[idx], bv = r1[idx];
        ((float4*)Rs)[idx] = make_float4(wa * a.x + wb * bv.x, wa * a.y + wb * bv.y,
                                         wa * a.z + wb * bv.z, wa * a.w + wb * bv.w);
        float4 ca = c0[idx], cb = c1[idx];
        ((float4*)Cs)[idx] = make_float4(wa * ca.x + wb * cb.x, wa * ca.y + wb * cb.y,
                                         wa * ca.z + wb * cb.z, wa * ca.w + wb * cb.w);
    }
    __syncthreads();

    int cq = t & 3;                // channel quad 0..3
    int p0 = t >> 2;               // pixel-in-chunk 0..63
    int cc = cq * 4;

    const float4* fmr = (const float4*)(fm + (size_t)(b * H + h) * (W * C));
    f32x4* orow = (f32x4*)(out + (size_t)(b * H + h) * (W * 48));

    float4 vcur = fmr[p0 * 4 + cq];    // k=0 pixel (wave-contiguous 1KB)
#pragma unroll
    for (int k = 0; k < 8; ++k) {
        int p = k * 64 + p0;
        // prefetch next chunk's fm value (index kept in-range; unused on last)
        int pn = (k < 7) ? (p + 64) : p;
        float4 vnext = fmr[pn * 4 + cq];

        float sw = 0.5f * p - 0.25f;
        float flw = floorf(sw);
        float fw = sw - flw;
        int j0i = max((int)flw, 0);
        int j1i = min((int)flw + 1, W2 - 1);
        float iw = 1.0f - fw;

        const float4 Ra = *(const float4*)(Rs + j0i * 16 + cc);
        const float4 Rb = *(const float4*)(Rs + j1i * 16 + cc);
        const float4 Ca = *(const float4*)(Cs + j0i * 16 + cc);
        const float4 Cb = *(const float4*)(Cs + j1i * 16 + cc);

        float4 dr = make_float4(vcur.x - (iw * Ra.x + fw * Rb.x),
                                vcur.y - (iw * Ra.y + fw * Rb.y),
                                vcur.z - (iw * Ra.z + fw * Rb.z),
                                vcur.w - (iw * Ra.w + fw * Rb.w));
        float4 dc = make_float4(vcur.x - (iw * Ca.x + fw * Cb.x),
                                vcur.y - (iw * Ca.y + fw * Cb.y),
                                vcur.z - (iw * Ca.z + fw * Cb.z),
                                vcur.w - (iw * Ca.w + fw * Cb.w));

        __syncthreads();                   // prev chunk's LDS reads done
        stage[p0 * 12 + cq]     = vcur;
        stage[p0 * 12 + 4 + cq] = dr;
        stage[p0 * 12 + 8 + cq] = dc;
        __syncthreads();                   // chunk staged

        int gbase = k * 768;
        float4 s0 = stage[t];
        float4 s1 = stage[t + 256];
        float4 s2 = stage[t + 512];
        f32x4 w0 = { s0.x, s0.y, s0.z, s0.w };
        f32x4 w1 = { s1.x, s1.y, s1.z, s1.w };
        f32x4 w2 = { s2.x, s2.y, s2.z, s2.w };
        __builtin_nontemporal_store(w0, &orow[gbase + t]);        // 1KB/wave
        __builtin_nontemporal_store(w1, &orow[gbase + t + 256]);
        __builtin_nontemporal_store(w2, &orow[gbase + t + 512]);

        vcur = vnext;
    }
}

extern "C" void kernel_launch(void* const* d_in, const int* in_sizes, int n_in,
                              void* d_out, int out_size, void* d_ws, size_t ws_size,
                              hipStream_t stream) {
    const float* fm   = (const float*)d_in[0];
    const float* kern = (const float*)d_in[1];
    const float* bias = (const float*)d_in[2];
    float* out = (float*)d_out;
    float* PP  = (float*)d_ws;                 // 2 x POOL_ELEMS partials
    float* ROW = PP + 2 * POOL_ELEMS;
    float* COL = ROW + POOL_ELEMS;

    pool_kernel<<<B * NP * CH * 2, 256, 0, stream>>>(fm, PP);
    conv_kernel<<<512, 256, 0, stream>>>(PP, kern, bias, ROW, COL);
    up_kernel<<<B * H, 256, 0, stream>>>(fm, ROW, COL, out);
}